// Round 9
// baseline (148.044 us; speedup 1.0000x reference)
//
#include <hip/hip_runtime.h>
#include <hip/hip_bf16.h>

#define BB 2
#define SS 2048
#define EE 1024
#define HH 16
#define DD 64
#define MT (BB*SS)     // 4096 tokens
#define NQ (3*EE)      // 3072

typedef unsigned short u16;
typedef __bf16 bf16t;
typedef bf16t bf16x8 __attribute__((ext_vector_type(8)));
typedef short short8v __attribute__((ext_vector_type(8)));
typedef float f32x4 __attribute__((ext_vector_type(4)));

#define AS1 __attribute__((address_space(1)))
#define AS3 __attribute__((address_space(3)))

__device__ __forceinline__ u16 f2b(float f) {
  unsigned u = __builtin_bit_cast(unsigned, f);
  u += 0x7FFF + ((u >> 16) & 1);   // RNE
  return (u16)(u >> 16);
}

__device__ __forceinline__ unsigned cvtpk(float lo, float hi) {
  unsigned r;
  asm("v_cvt_pk_bf16_f32 %0, %1, %2" : "=v"(r) : "v"(lo), "v"(hi));
  return r;
}

__device__ __forceinline__ void gload_lds16(const void* g, void* l) {
  __builtin_amdgcn_global_load_lds((const AS1 void*)(g), (AS3 void*)(l), 16, 0, 0);
}

__device__ __forceinline__ f32x4 mfma_bf16(short8v a, short8v b, f32x4 c) {
  return __builtin_amdgcn_mfma_f32_16x16x32_bf16(
      __builtin_bit_cast(bf16x8, a), __builtin_bit_cast(bf16x8, b), c, 0, 0, 0);
}

// scale folded into Q: 1/sqrt(64) * log2(e)
#define QSCALE 0.18033688f

// ---------------- prologue: cast x -> bf16 ----------------
__global__ void __launch_bounds__(256) cast_kernel(const float* __restrict__ in,
                                                   u16* __restrict__ out, int n) {
  int i = (blockIdx.x * 256 + threadIdx.x) * 4;
  if (i + 3 < n) {
    float4 v = *(const float4*)(in + i);
    ushort4 o;
    o.x = f2b(v.x); o.y = f2b(v.y); o.z = f2b(v.z); o.w = f2b(v.w);
    *(ushort4*)(out + i) = o;
  }
}

// W [K][N] f32 -> WT [N][K] bf16, 64x64 LDS tile (coalesced both sides)
__global__ void __launch_bounds__(256) transpose_kernel(const float* __restrict__ W,
                                                        u16* __restrict__ WT,
                                                        int K, int N) {
  __shared__ float t[64][65];
  int k0 = blockIdx.y * 64, n0 = blockIdx.x * 64;
  int r = threadIdx.x >> 4;          // 0..15
  int c4 = (threadIdx.x & 15) * 4;   // 0..60
#pragma unroll
  for (int i = 0; i < 4; ++i) {
    float4 v = *(const float4*)(W + (size_t)(k0 + r + i * 16) * N + n0 + c4);
    t[r + i * 16][c4 + 0] = v.x; t[r + i * 16][c4 + 1] = v.y;
    t[r + i * 16][c4 + 2] = v.z; t[r + i * 16][c4 + 3] = v.w;
  }
  __syncthreads();
#pragma unroll
  for (int i = 0; i < 4; ++i) {
    ushort4 o;
    o.x = f2b(t[c4 + 0][r + i * 16]); o.y = f2b(t[c4 + 1][r + i * 16]);
    o.z = f2b(t[c4 + 2][r + i * 16]); o.w = f2b(t[c4 + 3][r + i * 16]);
    *(ushort4*)(WT + (size_t)(n0 + r + i * 16) * K + k0 + c4) = o;
  }
}

// ---------------- QKV GEMM: C[4096,3072] = x @ Wqkv + b, scatter to Q,K,Vt ----------------
__global__ void __launch_bounds__(256) gemm_qkv_kernel(
    const u16* __restrict__ A, const u16* __restrict__ BT,
    const float* __restrict__ bias,
    u16* __restrict__ Qs, u16* __restrict__ Ks, u16* __restrict__ Vt) {
  __shared__ u16 As[4096];
  __shared__ u16 Bs[4096];
  const int K = EE;
  int tid = threadIdx.x;
  int w = tid >> 6, lane = tid & 63;
  int g = lane >> 4, q = lane & 15;
  int m0 = blockIdx.y * 128, n0 = blockIdx.x * 128;
  int wm = (w >> 1) * 64, wn = (w & 1) * 64;

  f32x4 acc[4][4] = {};

  int r = tid >> 2;
  int kc = (tid & 3) * 8;
  const u16* ga = A + (size_t)(m0 + r) * K + kc;
  const u16* gb = BT + (size_t)(n0 + r) * K + kc;
  u16* lA0 = As + w * 512;
  u16* lA1 = As + 2048 + w * 512;
  u16* lB0 = Bs + w * 512;
  u16* lB1 = Bs + 2048 + w * 512;

  for (int k0 = 0; k0 < K; k0 += 32) {
    gload_lds16(ga, lA0);
    gload_lds16(ga + 64 * K, lA1);
    gload_lds16(gb, lB0);
    gload_lds16(gb + 64 * K, lB1);
    ga += 32; gb += 32;
    __syncthreads();
    short8v af[4], bfv[4];
#pragma unroll
    for (int m = 0; m < 4; ++m)
      af[m] = *(const short8v*)(As + (wm + m * 16 + q) * 32 + g * 8);
#pragma unroll
    for (int n = 0; n < 4; ++n)
      bfv[n] = *(const short8v*)(Bs + (wn + n * 16 + q) * 32 + g * 8);
#pragma unroll
    for (int m = 0; m < 4; ++m)
#pragma unroll
      for (int n = 0; n < 4; ++n)
        acc[m][n] = mfma_bf16(af[m], bfv[n], acc[m][n]);
    __syncthreads();
  }

#pragma unroll
  for (int m = 0; m < 4; ++m) {
    int row0 = m0 + wm + m * 16 + g * 4;
#pragma unroll
    for (int n = 0; n < 4; ++n) {
      int col = n0 + wn + n * 16 + q;
      float bi = bias[col];
      int t = col >> 10;
      int h = (col >> 6) & 15;
      int d = col & 63;
#pragma unroll
      for (int r2 = 0; r2 < 4; ++r2) {
        int row = row0 + r2;
        int b = row >> 11, s = row & 2047;
        float v = acc[m][n][r2] + bi;
        size_t bh = (size_t)b * HH + h;
        if (t == 0)      Qs[(bh * SS + s) * DD + d] = f2b(v * QSCALE);
        else if (t == 1) Ks[(bh * SS + s) * DD + d] = f2b(v);
        else             Vt[(bh * DD + d) * SS + s] = f2b(v);
      }
    }
  }
}

// ---------------- causal flash attention (swapped QK^T, split-KV) ----------
// Block = 128 threads = 2 waves sharing ONE 32-row q-chunk; wave 0 takes KV
// tiles [0,ceil(nt/2)), wave 1 the rest (incl. diagonal). Partials merged at
// block end via LDS (f32 O, stride-68 rows; m/l). Total tile passes unchanged
// vs round 5, but 4096 waves -> 4 waves/SIMD latency hiding. 2048 blocks
// LPT-ordered (long chunks first). K/V direct from global (L2-resident).
// S^T = mfma(K,Q) keeps q-rows lane-local (2-shuffle reduce); P packed via
// cvt_pk into swizzled LDS; O^T = mfma(V^T,P); defer-max THR=8.
__global__ void __launch_bounds__(128) attn_kernel(
    const u16* __restrict__ Qg, const u16* __restrict__ Kg,
    const u16* __restrict__ Vg, u16* __restrict__ O) {
  __shared__ char lds[17408];          // P 2x4KB | Om 32x68 f32 | ml 256B
  int tid = threadIdx.x;
  int w = tid >> 6, lane = tid & 63;
  int g = lane >> 4, q = lane & 15;
  int id = blockIdx.x;                 // 0..2047
  int c = 63 - (id >> 5);              // LPT: longest chunks dispatch first
  int bh = id & 31;
  int qw = c * 32;
  char* Pw = lds + w * 4096;
  float* Om = (float*)(lds + 8192);    // [32][68] f32 (padded stride)
  float* Ml = (float*)(lds + 8192 + 8704);
  int qsw = (q & 7) << 4;              // P swizzle for this lane's rows

  const char* Qp = (const char*)Qg + (size_t)bh * (SS * 128);
  const char* Kp = (const char*)Kg + (size_t)bh * (SS * 128);
  const char* Vp = (const char*)Vg + (size_t)bh * (SS * 128);  // [d][s]

  short8v aq[2][2];
#pragma unroll
  for (int m = 0; m < 2; ++m)
#pragma unroll
    for (int j = 0; j < 2; ++j)
      aq[m][j] = *(const short8v*)(Qp + (size_t)(qw + m * 16 + q) * 128 + j * 64 + g * 16);

  f32x4 oacc[2][4] = {};               // O^T[d=vfi*16+g*4+r2][qrow=m*16+q]
  float mrun[2], lrun[2];
#pragma unroll
  for (int m = 0; m < 2; ++m) { mrun[m] = -1e30f; lrun[m] = 0.f; }

  const int nt = (qw >> 6) + 1;        // = c/2 + 1
  const int nth = (nt + 1) >> 1;
  const int tbeg = w ? nth : 0;
  const int tend = w ? nt : nth;

  for (int t = tbeg; t < tend; ++t) {
    int kv0 = t << 6;
    // ---- K fragments (L2-hot) ----
    short8v kf[4][2];
#pragma unroll
    for (int cc = 0; cc < 4; ++cc) {
      const char* kp = Kp + (size_t)(kv0 + cc * 16 + q) * 128 + g * 16;
      kf[cc][0] = *(const short8v*)kp;
      kf[cc][1] = *(const short8v*)(kp + 64);
    }
    // ---- S^T = K Q^T : lane holds S[qw+m*16+q][kv0 + cc*16 + g*4 + r2] ----
    f32x4 st[2][4];
#pragma unroll
    for (int m = 0; m < 2; ++m)
#pragma unroll
      for (int cc = 0; cc < 4; ++cc) {
        f32x4 z = {};
        z = mfma_bf16(kf[cc][0], aq[m][0], z);
        z = mfma_bf16(kf[cc][1], aq[m][1], z);
        st[m][cc] = z;
      }
    // ---- V^T fragments (issue early; latency hides under softmax) ----
    short8v vf[4][2];
#pragma unroll
    for (int v = 0; v < 4; ++v) {
      const char* vp = Vp + (size_t)(v * 16 + q) * (SS * 2) + (size_t)kv0 * 2 + g * 16;
      vf[v][0] = *(const short8v*)vp;
      vf[v][1] = *(const short8v*)(vp + 64);
    }
    // ---- causal mask (diagonal tile only) ----
    if (kv0 + 63 > qw) {
#pragma unroll
      for (int m = 0; m < 2; ++m) {
        int row = qw + m * 16 + q;
#pragma unroll
        for (int cc = 0; cc < 4; ++cc) {
          int kvb = kv0 + cc * 16 + g * 4;
#pragma unroll
          for (int r2 = 0; r2 < 4; ++r2)
            if (kvb + r2 > row) st[m][cc][r2] = -1e30f;
        }
      }
    }
    // ---- online softmax (base-2; row lane-local, 2 shuffles) + defer-max ----
#pragma unroll
    for (int m = 0; m < 2; ++m) {
      f32x4 t01, t23;
#pragma unroll
      for (int r2 = 0; r2 < 4; ++r2) {
        t01[r2] = fmaxf(st[m][0][r2], st[m][1][r2]);
        t23[r2] = fmaxf(st[m][2][r2], st[m][3][r2]);
      }
      float mx = fmaxf(fmaxf(fmaxf(t01[0], t01[1]), fmaxf(t01[2], t01[3])),
                       fmaxf(fmaxf(t23[0], t23[1]), fmaxf(t23[2], t23[3])));
      mx = fmaxf(mx, __shfl_xor(mx, 16));
      mx = fmaxf(mx, __shfl_xor(mx, 32));
      if (!__all(mx - mrun[m] <= 8.f)) {   // T13: rescale only on real growth
        float mnew = fmaxf(mrun[m], mx);
        float alpha = exp2f(mrun[m] - mnew);
        mrun[m] = mnew;
        lrun[m] *= alpha;
#pragma unroll
        for (int vfi = 0; vfi < 4; ++vfi)
#pragma unroll
          for (int r2 = 0; r2 < 4; ++r2) oacc[m][vfi][r2] *= alpha;
      }
      f32x4 sum4 = {};
#pragma unroll
      for (int cc = 0; cc < 4; ++cc)
#pragma unroll
        for (int r2 = 0; r2 < 4; ++r2) {
          float pv = exp2f(st[m][cc][r2] - mrun[m]);
          st[m][cc][r2] = pv;
          sum4[r2] += pv;
        }
      float s = (sum4[0] + sum4[1]) + (sum4[2] + sum4[3]);
      s += __shfl_xor(s, 16);
      s += __shfl_xor(s, 32);
      lrun[m] += s;
      // ---- P -> LDS packed bf16x2 (row = m*16+q, kv-contig) ----
      char* base = Pw + (m * 16 + q) * 128;
#pragma unroll
      for (int cc = 0; cc < 4; ++cc) {
        unsigned p01 = cvtpk(st[m][cc][0], st[m][cc][1]);
        unsigned p23 = cvtpk(st[m][cc][2], st[m][cc][3]);
        *(unsigned*)(base + ((32 * cc + 8 * g + 0) ^ qsw)) = p01;
        *(unsigned*)(base + ((32 * cc + 8 * g + 4) ^ qsw)) = p23;
      }
      short8v pa0 = *(const short8v*)(base + ((g * 16) ^ qsw));
      short8v pa1 = *(const short8v*)(base + ((64 + g * 16) ^ qsw));
      // ---- O^T += V^T P ----
#pragma unroll
      for (int vfi = 0; vfi < 4; ++vfi) {
        oacc[m][vfi] = mfma_bf16(vf[vfi][0], pa0, oacc[m][vfi]);
        oacc[m][vfi] = mfma_bf16(vf[vfi][1], pa1, oacc[m][vfi]);
      }
    }
  }

  // ---- merge the two KV halves ----
  if (w) {
#pragma unroll
    for (int m = 0; m < 2; ++m) {
      int row = m * 16 + q;
#pragma unroll
      for (int vfi = 0; vfi < 4; ++vfi)
        *(f32x4*)&Om[row * 68 + vfi * 16 + g * 4] = oacc[m][vfi];
      if (g == 0) { Ml[row] = mrun[m]; Ml[32 + row] = lrun[m]; }
    }
  }
  __syncthreads();
  if (!w) {
    int b = bh >> 4, h = bh & 15;
#pragma unroll
    for (int m = 0; m < 2; ++m) {
      int row = m * 16 + q;
      float m1 = Ml[row], l1 = Ml[32 + row];
      float mf = fmaxf(mrun[m], m1);
      float a0 = exp2f(mrun[m] - mf);
      float a1 = exp2f(m1 - mf);
      float inv = 1.0f / (a0 * lrun[m] + a1 * l1);
      a0 *= inv; a1 *= inv;
      char* obase = (char*)O + (((size_t)b * SS + qw + row) * EE + h * 64) * 2;
#pragma unroll
      for (int vfi = 0; vfi < 4; ++vfi) {
        f32x4 o1 = *(const f32x4*)&Om[row * 68 + vfi * 16 + g * 4];
        uint2 o;
        o.x = cvtpk(a0 * oacc[m][vfi][0] + a1 * o1[0],
                    a0 * oacc[m][vfi][1] + a1 * o1[1]);
        o.y = cvtpk(a0 * oacc[m][vfi][2] + a1 * o1[2],
                    a0 * oacc[m][vfi][3] + a1 * o1[3]);
        *(uint2*)(obase + (vfi * 16 + g * 4) * 2) = o;
      }
    }
  }
}

// ---------------- output projection GEMM: out[4096,1024] = O @ Wout + bout (f32) ----------------
__global__ void __launch_bounds__(256) gemm_out_kernel(
    const u16* __restrict__ A, const u16* __restrict__ BT,
    const float* __restrict__ bias, float* __restrict__ Cout) {
  __shared__ u16 As[4096];
  __shared__ u16 Bs[4096];
  const int K = EE;
  int tid = threadIdx.x;
  int w = tid >> 6, lane = tid & 63;
  int g = lane >> 4, q = lane & 15;
  int m0 = blockIdx.y * 128, n0 = blockIdx.x * 128;
  int wm = (w >> 1) * 64, wn = (w & 1) * 64;

  f32x4 acc[4][4] = {};

  int r = tid >> 2;
  int kc = (tid & 3) * 8;
  const u16* ga = A + (size_t)(m0 + r) * K + kc;
  const u16* gb = BT + (size_t)(n0 + r) * K + kc;
  u16* lA0 = As + w * 512;
  u16* lA1 = As + 2048 + w * 512;
  u16* lB0 = Bs + w * 512;
  u16* lB1 = Bs + 2048 + w * 512;

  for (int k0 = 0; k0 < K; k0 += 32) {
    gload_lds16(ga, lA0);
    gload_lds16(ga + 64 * K, lA1);
    gload_lds16(gb, lB0);
    gload_lds16(gb + 64 * K, lB1);
    ga += 32; gb += 32;
    __syncthreads();
    short8v af[4], bfv[4];
#pragma unroll
    for (int m = 0; m < 4; ++m)
      af[m] = *(const short8v*)(As + (wm + m * 16 + q) * 32 + g * 8);
#pragma unroll
    for (int n = 0; n < 4; ++n)
      bfv[n] = *(const short8v*)(Bs + (wn + n * 16 + q) * 32 + g * 8);
#pragma unroll
    for (int m = 0; m < 4; ++m)
#pragma unroll
      for (int n = 0; n < 4; ++n)
        acc[m][n] = mfma_bf16(af[m], bfv[n], acc[m][n]);
    __syncthreads();
  }

#pragma unroll
  for (int m = 0; m < 4; ++m) {
    int row0 = m0 + wm + m * 16 + g * 4;
#pragma unroll
    for (int n = 0; n < 4; ++n) {
      int col = n0 + wn + n * 16 + q;
      float bi = bias[col];
#pragma unroll
      for (int r2 = 0; r2 < 4; ++r2) {
        int row = row0 + r2;
        Cout[(size_t)row * EE + col] = acc[m][n][r2] + bi;
      }
    }
  }
}

extern "C" void kernel_launch(void* const* d_in, const int* in_sizes, int n_in,
                              void* d_out, int out_size, void* d_ws, size_t ws_size,
                              hipStream_t stream) {
  (void)in_sizes; (void)n_in; (void)out_size; (void)ws_size;
  const float* x    = (const float*)d_in[0];
  const float* Wqkv = (const float*)d_in[1];
  const float* bqkv = (const float*)d_in[2];
  const float* Wout = (const float*)d_in[3];
  const float* bout = (const float*)d_in[4];
  float* out = (float*)d_out;

  char* p = (char*)d_ws;
  u16* xb  = (u16*)p; p += (size_t)MT * EE * 2;           // 8 MB
  u16* wqT = (u16*)p; p += (size_t)NQ * EE * 2;           // 6 MB
  u16* woT = (u16*)p; p += (size_t)EE * EE * 2;           // 2 MB
  u16* Qs  = (u16*)p; p += (size_t)BB * HH * SS * DD * 2; // 8 MB
  u16* Ks  = (u16*)p; p += (size_t)BB * HH * SS * DD * 2; // 8 MB
  u16* Vt  = (u16*)p; p += (size_t)BB * HH * DD * SS * 2; // 8 MB
  u16* Ob  = (u16*)p; p += (size_t)MT * EE * 2;           // 8 MB

  cast_kernel<<<dim3((MT * EE / 4) / 256), dim3(256), 0, stream>>>(x, xb, MT * EE);
  transpose_kernel<<<dim3(NQ / 64, EE / 64), dim3(256), 0, stream>>>(Wqkv, wqT, EE, NQ);
  transpose_kernel<<<dim3(EE / 64, EE / 64), dim3(256), 0, stream>>>(Wout, woT, EE, EE);
  gemm_qkv_kernel<<<dim3(NQ / 128, MT / 128), dim3(256), 0, stream>>>(xb, wqT, bqkv, Qs, Ks, Vt);
  attn_kernel<<<dim3(2048), dim3(128), 0, stream>>>(Qs, Ks, Vt, Ob);
  gemm_out_kernel<<<dim3(EE / 128, MT / 128), dim3(256), 0, stream>>>(Ob, woT, bout, out);
}

// Round 10
// 133.329 us; speedup vs baseline: 1.1104x; 1.1104x over previous
//
#include <hip/hip_runtime.h>
#include <hip/hip_bf16.h>

#define BB 2
#define SS 2048
#define EE 1024
#define HH 16
#define DD 64
#define MT (BB*SS)     // 4096 tokens
#define NQ (3*EE)      // 3072

typedef unsigned short u16;
typedef __bf16 bf16t;
typedef bf16t bf16x8 __attribute__((ext_vector_type(8)));
typedef short short8v __attribute__((ext_vector_type(8)));
typedef float f32x4 __attribute__((ext_vector_type(4)));

#define AS1 __attribute__((address_space(1)))
#define AS3 __attribute__((address_space(3)))

__device__ __forceinline__ u16 f2b(float f) {
  unsigned u = __builtin_bit_cast(unsigned, f);
  u += 0x7FFF + ((u >> 16) & 1);   // RNE
  return (u16)(u >> 16);
}

__device__ __forceinline__ unsigned cvtpk(float lo, float hi) {
  unsigned r;
  asm("v_cvt_pk_bf16_f32 %0, %1, %2" : "=v"(r) : "v"(lo), "v"(hi));
  return r;
}

__device__ __forceinline__ void gload_lds16(const void* g, void* l) {
  __builtin_amdgcn_global_load_lds((const AS1 void*)(g), (AS3 void*)(l), 16, 0, 0);
}

__device__ __forceinline__ f32x4 mfma_bf16(short8v a, short8v b, f32x4 c) {
  return __builtin_amdgcn_mfma_f32_16x16x32_bf16(
      __builtin_bit_cast(bf16x8, a), __builtin_bit_cast(bf16x8, b), c, 0, 0, 0);
}

// scale folded into Q: 1/sqrt(64) * log2(e)
#define QSCALE 0.18033688f

// ---------------- prologue: cast x -> bf16 ----------------
__global__ void __launch_bounds__(256) cast_kernel(const float* __restrict__ in,
                                                   u16* __restrict__ out, int n) {
  int i = (blockIdx.x * 256 + threadIdx.x) * 4;
  if (i + 3 < n) {
    float4 v = *(const float4*)(in + i);
    ushort4 o;
    o.x = f2b(v.x); o.y = f2b(v.y); o.z = f2b(v.z); o.w = f2b(v.w);
    *(ushort4*)(out + i) = o;
  }
}

// W [K][N] f32 -> WT [N][K] bf16, 64x64 LDS tile (coalesced both sides)
__global__ void __launch_bounds__(256) transpose_kernel(const float* __restrict__ W,
                                                        u16* __restrict__ WT,
                                                        int K, int N) {
  __shared__ float t[64][65];
  int k0 = blockIdx.y * 64, n0 = blockIdx.x * 64;
  int r = threadIdx.x >> 4;          // 0..15
  int c4 = (threadIdx.x & 15) * 4;   // 0..60
#pragma unroll
  for (int i = 0; i < 4; ++i) {
    float4 v = *(const float4*)(W + (size_t)(k0 + r + i * 16) * N + n0 + c4);
    t[r + i * 16][c4 + 0] = v.x; t[r + i * 16][c4 + 1] = v.y;
    t[r + i * 16][c4 + 2] = v.z; t[r + i * 16][c4 + 3] = v.w;
  }
  __syncthreads();
#pragma unroll
  for (int i = 0; i < 4; ++i) {
    ushort4 o;
    o.x = f2b(t[c4 + 0][r + i * 16]); o.y = f2b(t[c4 + 1][r + i * 16]);
    o.z = f2b(t[c4 + 2][r + i * 16]); o.w = f2b(t[c4 + 3][r + i * 16]);
    *(ushort4*)(WT + (size_t)(n0 + r + i * 16) * K + k0 + c4) = o;
  }
}

// ---------------- QKV GEMM: C[4096,3072] = x @ Wqkv + b, scatter to Q,K,Vt ----------------
__global__ void __launch_bounds__(256) gemm_qkv_kernel(
    const u16* __restrict__ A, const u16* __restrict__ BT,
    const float* __restrict__ bias,
    u16* __restrict__ Qs, u16* __restrict__ Ks, u16* __restrict__ Vt) {
  __shared__ u16 As[4096];
  __shared__ u16 Bs[4096];
  const int K = EE;
  int tid = threadIdx.x;
  int w = tid >> 6, lane = tid & 63;
  int g = lane >> 4, q = lane & 15;
  int m0 = blockIdx.y * 128, n0 = blockIdx.x * 128;
  int wm = (w >> 1) * 64, wn = (w & 1) * 64;

  f32x4 acc[4][4] = {};

  int r = tid >> 2;
  int kc = (tid & 3) * 8;
  const u16* ga = A + (size_t)(m0 + r) * K + kc;
  const u16* gb = BT + (size_t)(n0 + r) * K + kc;
  u16* lA0 = As + w * 512;
  u16* lA1 = As + 2048 + w * 512;
  u16* lB0 = Bs + w * 512;
  u16* lB1 = Bs + 2048 + w * 512;

  for (int k0 = 0; k0 < K; k0 += 32) {
    gload_lds16(ga, lA0);
    gload_lds16(ga + 64 * K, lA1);
    gload_lds16(gb, lB0);
    gload_lds16(gb + 64 * K, lB1);
    ga += 32; gb += 32;
    __syncthreads();
    short8v af[4], bfv[4];
#pragma unroll
    for (int m = 0; m < 4; ++m)
      af[m] = *(const short8v*)(As + (wm + m * 16 + q) * 32 + g * 8);
#pragma unroll
    for (int n = 0; n < 4; ++n)
      bfv[n] = *(const short8v*)(Bs + (wn + n * 16 + q) * 32 + g * 8);
#pragma unroll
    for (int m = 0; m < 4; ++m)
#pragma unroll
      for (int n = 0; n < 4; ++n)
        acc[m][n] = mfma_bf16(af[m], bfv[n], acc[m][n]);
    __syncthreads();
  }

#pragma unroll
  for (int m = 0; m < 4; ++m) {
    int row0 = m0 + wm + m * 16 + g * 4;
#pragma unroll
    for (int n = 0; n < 4; ++n) {
      int col = n0 + wn + n * 16 + q;
      float bi = bias[col];
      int t = col >> 10;
      int h = (col >> 6) & 15;
      int d = col & 63;
#pragma unroll
      for (int r2 = 0; r2 < 4; ++r2) {
        int row = row0 + r2;
        int b = row >> 11, s = row & 2047;
        float v = acc[m][n][r2] + bi;
        size_t bh = (size_t)b * HH + h;
        if (t == 0)      Qs[(bh * SS + s) * DD + d] = f2b(v * QSCALE);
        else if (t == 1) Ks[(bh * SS + s) * DD + d] = f2b(v);
        else             Vt[(bh * DD + d) * SS + s] = f2b(v);
      }
    }
  }
}

// ---------------- causal flash attention (8-wave LDS-staged, swapped QK^T) --
// Block = 512 threads = 8 waves x 16 q-rows = 128-row chunk; chunks paired
// (p, 15-p) -> 256 blocks x exactly 34 KV tiles each (uniform). K/V tiles
// (64x64 bf16 each) staged ONCE per block into double-buffered LDS via
// global_load_lds (2 loads/thread/tile), XOR-swizzled per rule 21 (linear
// dest + inverse-swizzled global src + swizzled ds_read_b128 = 2-way free).
// stage(t+1) issued before compute(t); one __syncthreads per tile. Swapped
// S^T = mfma(K,Q) keeps q-rows lane-local (2-shuffle reduce); P packed via
// cvt_pk into per-wave swizzled LDS; O^T = mfma(V^T,P); defer-max THR=8.
__global__ void __launch_bounds__(512) attn_kernel(
    const u16* __restrict__ Qg, const u16* __restrict__ Kg,
    const u16* __restrict__ Vg, u16* __restrict__ O) {
  __shared__ char lds[49152];          // K0 8K | K1 8K | V0 8K | V1 8K | P 8x2K
  const int tid = threadIdx.x;
  const int w = tid >> 6, lane = tid & 63;
  const int g = lane >> 4, q = lane & 15;
  const int bid = blockIdx.x;          // 0..255
  const int bh = bid & 31;             // bid%8 -> XCD; K/V L2-resident
  const int p = bid >> 3 >> 2;         // 0..7  (bid>>5)
  const int b = bh >> 4, h = bh & 15;
  char* Pw = lds + 32768 + w * 2048;
  const int qsw = (q & 7) << 4;        // swizzle for this lane's rows (row&7 == q&7)

  const char* Qp = (const char*)Qg + (size_t)bh * (SS * 128);
  const char* Kp = (const char*)Kg + (size_t)bh * (SS * 128);
  const char* Vp = (const char*)Vg + (size_t)bh * (SS * 128);  // [d][s]

  // staging map: thread -> (row 0..63, 16B chunk), inverse-swizzled source col
  const int srow = tid >> 3;
  const int ssw = ((tid & 7) * 16) ^ ((srow & 7) << 4);
  const char* Ksrc = Kp + srow * 128 + ssw;        // + kv0*128
  const char* Vsrc = Vp + (size_t)srow * (SS * 2) + ssw;  // + kv0*2
  char* Kdst = lds + w * 1024;          // + buf*8192 (lane*16 added by HW)
  char* Vdst = lds + 16384 + w * 1024;

  const int sl = 2 * p + 2;            // low-chunk tiles; total = 34
  int chunk = p;
  int kvbase = 0;
  int qw = chunk * 128 + w * 16;

  short8v aq0 = *(const short8v*)(Qp + (size_t)(qw + q) * 128 + g * 16);
  short8v aq1 = *(const short8v*)(Qp + (size_t)(qw + q) * 128 + 64 + g * 16);

  f32x4 oacc[4] = {};                  // O^T[d=vfi*16+g*4+r2][qrow=qw+q]
  float mrun = -1e30f, lrun = 0.f;

  // prologue: stage tile 0
  gload_lds16(Ksrc, Kdst);
  gload_lds16(Vsrc, Vdst);
  __syncthreads();

  for (int s = 0; s < 34; ++s) {
    const int buf = s & 1;
    if (s + 1 < 34) {                  // issue next-tile staging before compute
      int s2 = s + 1;
      int kv2 = ((s2 < sl) ? s2 : (s2 - sl)) << 6;
      gload_lds16(Ksrc + (size_t)kv2 * 128, Kdst + (buf ^ 1) * 8192);
      gload_lds16(Vsrc + kv2 * 2, Vdst + (buf ^ 1) * 8192);
    }
    const int kv0 = (s - kvbase) << 6;
    if (kv0 <= qw + 15) {              // wave has unmasked work this tile
      const char* Kc = lds + buf * 8192;
      const char* Vc = lds + 16384 + buf * 8192;
      // ---- K fragments from swizzled LDS ----
      short8v kf[4][2];
#pragma unroll
      for (int cc = 0; cc < 4; ++cc) {
        const char* kb = Kc + (cc * 16 + q) * 128;
        kf[cc][0] = *(const short8v*)(kb + ((g * 16) ^ qsw));
        kf[cc][1] = *(const short8v*)(kb + ((64 + g * 16) ^ qsw));
      }
      // ---- S^T = K Q^T : lane holds S[qw+q][kv0 + cc*16 + g*4 + r2] ----
      f32x4 st[4];
#pragma unroll
      for (int cc = 0; cc < 4; ++cc) {
        f32x4 z = {};
        z = mfma_bf16(kf[cc][0], aq0, z);
        z = mfma_bf16(kf[cc][1], aq1, z);
        st[cc] = z;
      }
      // ---- V^T fragments from swizzled LDS ----
      short8v vf[4][2];
#pragma unroll
      for (int v = 0; v < 4; ++v) {
        const char* vb = Vc + (v * 16 + q) * 128;
        vf[v][0] = *(const short8v*)(vb + ((g * 16) ^ qsw));
        vf[v][1] = *(const short8v*)(vb + ((64 + g * 16) ^ qsw));
      }
      // ---- causal mask (diagonal tiles only) ----
      if (kv0 + 63 > qw) {
        int row = qw + q;
#pragma unroll
        for (int cc = 0; cc < 4; ++cc) {
          int kvb = kv0 + cc * 16 + g * 4;
#pragma unroll
          for (int r2 = 0; r2 < 4; ++r2)
            if (kvb + r2 > row) st[cc][r2] = -1e30f;
        }
      }
      // ---- online softmax (base-2; row lane-local, 2 shuffles) + defer-max --
      f32x4 t01, t23;
#pragma unroll
      for (int r2 = 0; r2 < 4; ++r2) {
        t01[r2] = fmaxf(st[0][r2], st[1][r2]);
        t23[r2] = fmaxf(st[2][r2], st[3][r2]);
      }
      float mx = fmaxf(fmaxf(fmaxf(t01[0], t01[1]), fmaxf(t01[2], t01[3])),
                       fmaxf(fmaxf(t23[0], t23[1]), fmaxf(t23[2], t23[3])));
      mx = fmaxf(mx, __shfl_xor(mx, 16));
      mx = fmaxf(mx, __shfl_xor(mx, 32));
      if (!__all(mx - mrun <= 8.f)) {  // T13: rescale only on real growth
        float mnew = fmaxf(mrun, mx);
        float alpha = exp2f(mrun - mnew);
        mrun = mnew;
        lrun *= alpha;
#pragma unroll
        for (int vfi = 0; vfi < 4; ++vfi)
#pragma unroll
          for (int r2 = 0; r2 < 4; ++r2) oacc[vfi][r2] *= alpha;
      }
      f32x4 sum4 = {};
#pragma unroll
      for (int cc = 0; cc < 4; ++cc)
#pragma unroll
        for (int r2 = 0; r2 < 4; ++r2) {
          float pv = exp2f(st[cc][r2] - mrun);
          st[cc][r2] = pv;
          sum4[r2] += pv;
        }
      float sm = (sum4[0] + sum4[1]) + (sum4[2] + sum4[3]);
      sm += __shfl_xor(sm, 16);
      sm += __shfl_xor(sm, 32);
      lrun += sm;
      // ---- P -> per-wave LDS packed bf16x2 (row = q, kv-contig) ----
      char* basep = Pw + q * 128;
#pragma unroll
      for (int cc = 0; cc < 4; ++cc) {
        unsigned p01 = cvtpk(st[cc][0], st[cc][1]);
        unsigned p23 = cvtpk(st[cc][2], st[cc][3]);
        *(unsigned*)(basep + ((32 * cc + 8 * g + 0) ^ qsw)) = p01;
        *(unsigned*)(basep + ((32 * cc + 8 * g + 4) ^ qsw)) = p23;
      }
      short8v pa0 = *(const short8v*)(basep + ((g * 16) ^ qsw));
      short8v pa1 = *(const short8v*)(basep + ((64 + g * 16) ^ qsw));
      // ---- O^T += V^T P ----
#pragma unroll
      for (int vfi = 0; vfi < 4; ++vfi) {
        oacc[vfi] = mfma_bf16(vf[vfi][0], pa0, oacc[vfi]);
        oacc[vfi] = mfma_bf16(vf[vfi][1], pa1, oacc[vfi]);
      }
    }
    __syncthreads();                   // staged loads drained; buffers safe
    if (s == sl - 1) {
      // ---- low-chunk epilogue, then switch to complementary high chunk ----
      float inv = 1.0f / lrun;
      int row = qw + q;
      char* obase = (char*)O + (((size_t)b * SS + row) * EE + h * 64) * 2;
#pragma unroll
      for (int vfi = 0; vfi < 4; ++vfi) {
        uint2 o;
        o.x = cvtpk(oacc[vfi][0] * inv, oacc[vfi][1] * inv);
        o.y = cvtpk(oacc[vfi][2] * inv, oacc[vfi][3] * inv);
        *(uint2*)(obase + (vfi * 16 + g * 4) * 2) = o;
      }
      chunk = 15 - p;
      kvbase = sl;
      qw = chunk * 128 + w * 16;
      aq0 = *(const short8v*)(Qp + (size_t)(qw + q) * 128 + g * 16);
      aq1 = *(const short8v*)(Qp + (size_t)(qw + q) * 128 + 64 + g * 16);
#pragma unroll
      for (int vfi = 0; vfi < 4; ++vfi)
#pragma unroll
        for (int r2 = 0; r2 < 4; ++r2) oacc[vfi][r2] = 0.f;
      mrun = -1e30f; lrun = 0.f;
    }
  }

  // ---- high-chunk epilogue ----
  {
    float inv = 1.0f / lrun;
    int row = qw + q;
    char* obase = (char*)O + (((size_t)b * SS + row) * EE + h * 64) * 2;
#pragma unroll
    for (int vfi = 0; vfi < 4; ++vfi) {
      uint2 o;
      o.x = cvtpk(oacc[vfi][0] * inv, oacc[vfi][1] * inv);
      o.y = cvtpk(oacc[vfi][2] * inv, oacc[vfi][3] * inv);
      *(uint2*)(obase + (vfi * 16 + g * 4) * 2) = o;
    }
  }
}

// ---------------- output projection GEMM: out[4096,1024] = O @ Wout + bout (f32) ----------------
__global__ void __launch_bounds__(256) gemm_out_kernel(
    const u16* __restrict__ A, const u16* __restrict__ BT,
    const float* __restrict__ bias, float* __restrict__ Cout) {
  __shared__ u16 As[4096];
  __shared__ u16 Bs[4096];
  const int K = EE;
  int tid = threadIdx.x;
  int w = tid >> 6, lane = tid & 63;
  int g = lane >> 4, q = lane & 15;
  int m0 = blockIdx.y * 128, n0 = blockIdx.x * 128;
  int wm = (w >> 1) * 64, wn = (w & 1) * 64;

  f32x4 acc[4][4] = {};

  int r = tid >> 2;
  int kc = (tid & 3) * 8;
  const u16* ga = A + (size_t)(m0 + r) * K + kc;
  const u16* gb = BT + (size_t)(n0 + r) * K + kc;
  u16* lA0 = As + w * 512;
  u16* lA1 = As + 2048 + w * 512;
  u16* lB0 = Bs + w * 512;
  u16* lB1 = Bs + 2048 + w * 512;

  for (int k0 = 0; k0 < K; k0 += 32) {
    gload_lds16(ga, lA0);
    gload_lds16(ga + 64 * K, lA1);
    gload_lds16(gb, lB0);
    gload_lds16(gb + 64 * K, lB1);
    ga += 32; gb += 32;
    __syncthreads();
    short8v af[4], bfv[4];
#pragma unroll
    for (int m = 0; m < 4; ++m)
      af[m] = *(const short8v*)(As + (wm + m * 16 + q) * 32 + g * 8);
#pragma unroll
    for (int n = 0; n < 4; ++n)
      bfv[n] = *(const short8v*)(Bs + (wn + n * 16 + q) * 32 + g * 8);
#pragma unroll
    for (int m = 0; m < 4; ++m)
#pragma unroll
      for (int n = 0; n < 4; ++n)
        acc[m][n] = mfma_bf16(af[m], bfv[n], acc[m][n]);
    __syncthreads();
  }

#pragma unroll
  for (int m = 0; m < 4; ++m) {
    int row0 = m0 + wm + m * 16 + g * 4;
#pragma unroll
    for (int n = 0; n < 4; ++n) {
      int col = n0 + wn + n * 16 + q;
      float bi = bias[col];
#pragma unroll
      for (int r2 = 0; r2 < 4; ++r2) {
        int row = row0 + r2;
        Cout[(size_t)row * EE + col] = acc[m][n][r2] + bi;
      }
    }
  }
}

extern "C" void kernel_launch(void* const* d_in, const int* in_sizes, int n_in,
                              void* d_out, int out_size, void* d_ws, size_t ws_size,
                              hipStream_t stream) {
  (void)in_sizes; (void)n_in; (void)out_size; (void)ws_size;
  const float* x    = (const float*)d_in[0];
  const float* Wqkv = (const float*)d_in[1];
  const float* bqkv = (const float*)d_in[2];
  const float* Wout = (const float*)d_in[3];
  const float* bout = (const float*)d_in[4];
  float* out = (float*)d_out;

  char* p = (char*)d_ws;
  u16* xb  = (u16*)p; p += (size_t)MT * EE * 2;           // 8 MB
  u16* wqT = (u16*)p; p += (size_t)NQ * EE * 2;           // 6 MB
  u16* woT = (u16*)p; p += (size_t)EE * EE * 2;           // 2 MB
  u16* Qs  = (u16*)p; p += (size_t)BB * HH * SS * DD * 2; // 8 MB
  u16* Ks  = (u16*)p; p += (size_t)BB * HH * SS * DD * 2; // 8 MB
  u16* Vt  = (u16*)p; p += (size_t)BB * HH * DD * SS * 2; // 8 MB
  u16* Ob  = (u16*)p; p += (size_t)MT * EE * 2;           // 8 MB

  cast_kernel<<<dim3((MT * EE / 4) / 256), dim3(256), 0, stream>>>(x, xb, MT * EE);
  transpose_kernel<<<dim3(NQ / 64, EE / 64), dim3(256), 0, stream>>>(Wqkv, wqT, EE, NQ);
  transpose_kernel<<<dim3(EE / 64, EE / 64), dim3(256), 0, stream>>>(Wout, woT, EE, EE);
  gemm_qkv_kernel<<<dim3(NQ / 128, MT / 128), dim3(256), 0, stream>>>(xb, wqT, bqkv, Qs, Ks, Vt);
  attn_kernel<<<dim3(256), dim3(512), 0, stream>>>(Qs, Ks, Vt, Ob);
  gemm_out_kernel<<<dim3(EE / 128, MT / 128), dim3(256), 0, stream>>>(Ob, woT, bout, out);
}